// Round 22
// baseline (86.326 us; speedup 1.0000x reference)
//
#include <hip/hip_runtime.h>

#define F_DIMC 64
#define K_DIMC 16
#define NGRAPH 64
#define NXCD 8
#define SX_SPLIT 16
#define NB_SEL 400                         // N/256
#define NB_CHUNK 256                       // histogram/scatter chunks
#define NB_ZERO 64
#define CHUNK_I4 800                       // int4s per chunk (256*800 = E/4)
#define ADJ_BLOCKS 256                     // 4/graph
#define ADJ_OFF (NGRAPH * K_DIMC * F_DIMC)
#define LOSS_OFF (ADJ_OFF + NGRAPH * K_DIMC * K_DIMC)
#define ZERO_BYTES 394240

typedef __attribute__((ext_vector_type(8))) short s16x8;
typedef __attribute__((ext_vector_type(4))) float f32x4;

// ---------------- workspace layout (bytes) ----------------
// zeroed each call (zero-role blocks of k_sel_hist): [0, 394240)
//   [0,256) den | [256,512) donecnt | [512,768) lossws | [768,1024) pad
//   [1024,66560) dense_raw | [66560,132096) ssbuf | [132096,394240) sxbuf
// not zeroed:
//   [394240,394496) offsets | [394496,394752) gtot
//   [394752,460288) blockhist (int[256][64]) | [460288,525824) chunkbase
//   [525824,7079424) sel (float[N*16]) | [7079424,13633024) sorted (uint2[E])

__device__ inline unsigned short f2bf(float f) {
    unsigned u = __builtin_bit_cast(unsigned, f);
    u += 0x7fffu + ((u >> 16) & 1u);       // RNE
    return (unsigned short)(u >> 16);
}

// ---- fused: selection [0,NB_SEL) || per-chunk histogram || ws zeroing ----
__global__ __launch_bounds__(256) void k_sel_hist(const float* __restrict__ node_attr,
                                                  const float* __restrict__ W,
                                                  const float* __restrict__ bias,
                                                  const int* __restrict__ row,
                                                  float* __restrict__ sel,
                                                  int* __restrict__ blockhist,
                                                  float4* __restrict__ zdst,
                                                  int N, int perG) {
    int t = threadIdx.x;
    if (blockIdx.x < NB_SEL) {
        __shared__ float sW[K_DIMC][F_DIMC];
        __shared__ float sb[K_DIMC];
        for (int idx = t; idx < F_DIMC * K_DIMC; idx += 256) {
            int f = idx / K_DIMC, k = idx % K_DIMC;
            sW[k][f] = W[idx];
        }
        if (t < K_DIMC) sb[t] = bias[t];
        __syncthreads();
        int n = blockIdx.x * 256 + t;
        if (n >= N) return;

        const float4* xr = (const float4*)(node_attr + (size_t)n * F_DIMC);
        float4 x[F_DIMC / 4];
#pragma unroll
        for (int f4 = 0; f4 < F_DIMC / 4; ++f4) x[f4] = xr[f4];

        float logits[K_DIMC];
#pragma unroll
        for (int k = 0; k < K_DIMC; ++k) {
            const float4* wk = (const float4*)&sW[k][0];
            float acc = sb[k];
#pragma unroll
            for (int f4 = 0; f4 < F_DIMC / 4; ++f4) {
                float4 w = wk[f4];
                acc += x[f4].x * w.x + x[f4].y * w.y + x[f4].z * w.z + x[f4].w * w.w;
            }
            logits[k] = acc;
        }
        float m = logits[0];
#pragma unroll
        for (int k = 1; k < K_DIMC; ++k) m = fmaxf(m, logits[k]);
        float sum = 0.f;
#pragma unroll
        for (int k = 0; k < K_DIMC; ++k) {
            float e = __expf(logits[k] - m);
            logits[k] = e;
            sum += e;
        }
        float inv = 1.f / sum;
        float4* sd = (float4*)(sel + (size_t)n * K_DIMC);
#pragma unroll
        for (int k4 = 0; k4 < K_DIMC / 4; ++k4) {
            float4 v;
            v.x = logits[4 * k4 + 0] * inv;
            v.y = logits[4 * k4 + 1] * inv;
            v.z = logits[4 * k4 + 2] * inv;
            v.w = logits[4 * k4 + 3] * inv;
            sd[k4] = v;
        }
    } else if (blockIdx.x < NB_SEL + NB_CHUNK) {
        __shared__ int lh[NGRAPH];
        int h = blockIdx.x - NB_SEL;                 // 0..255, static chunk
        if (t < NGRAPH) lh[t] = 0;
        __syncthreads();
        for (int i = t; i < CHUNK_I4; i += 256) {
            int4 r4 = ((const int4*)row)[h * CHUNK_I4 + i];
            atomicAdd(&lh[r4.x / perG], 1);
            atomicAdd(&lh[r4.y / perG], 1);
            atomicAdd(&lh[r4.z / perG], 1);
            atomicAdd(&lh[r4.w / perG], 1);
        }
        __syncthreads();
        if (t < NGRAPH) blockhist[h * NGRAPH + t] = lh[t];
    } else {
        int z = blockIdx.x - NB_SEL - NB_CHUNK;
        for (int i = z * 256 + t; i < ZERO_BYTES / 16; i += NB_ZERO * 256)
            zdst[i] = make_float4(0.f, 0.f, 0.f, 0.f);
    }
}

// ---- per-graph exclusive scan over 256 chunks: chunkbase[b][g], gtot[g] ----
__global__ __launch_bounds__(256) void k_chunkscan(const int* __restrict__ blockhist,
                                                   int* __restrict__ chunkbase,
                                                   int* __restrict__ gtot) {
    int g = blockIdx.x;
    int t = threadIdx.x;                 // 0..255 = chunk index
    int lane = t & 63;
    int wid = t >> 6;
    int v = blockhist[t * NGRAPH + g];
    int s = v;
#pragma unroll
    for (int d = 1; d < 64; d <<= 1) {
        int o = __shfl_up(s, d);
        if (lane >= d) s += o;
    }
    __shared__ int wsum[4];
    if (lane == 63) wsum[wid] = s;
    __syncthreads();
    int pre = 0;
#pragma unroll
    for (int w = 0; w < 4; ++w) pre += (w < wid) ? wsum[w] : 0;
    int incl = s + pre;
    chunkbase[t * NGRAPH + g] = incl - v;
    if (t == 255) gtot[g] = incl;
}

// ---- fused scatter || SX/SS, 5-stride role interleave (both co-resident):
// b%5==0 -> scatter chunk b/5 (256 chunks: scattered 8B writes, int pipe);
// else   -> sx slot (1024 slots = 16 splits x 64 graphs, 4 waves each:
//           streaming 32.5MB reads + FMA). Different resources -> overlap
// (unlike r8-r10's two gather-bound roles). 1280 blocks, 21KB LDS, 7/CU.
__global__ __launch_bounds__(256) void k_scatter_sx(const int* __restrict__ row,
                                                    const int* __restrict__ col,
                                                    const int* __restrict__ gtot,
                                                    const int* __restrict__ chunkbase,
                                                    int* __restrict__ offsets,
                                                    uint2* __restrict__ sorted,
                                                    const float* __restrict__ sel,
                                                    const float* __restrict__ x,
                                                    float* __restrict__ ssbuf,
                                                    float* __restrict__ sxbuf,
                                                    int perG) {
    int b = blockIdx.x;
    int r5 = b % 5;
    int t = threadIdx.x;
    if (r5 == 0) {
        // ---------------- scatter role ----------------
        __shared__ int base_[NGRAPH];
        __shared__ int lcnt[NGRAPH];
        int h = b / 5;                   // 0..255, same chunk as hist
        if (t < 64) {
            int v = gtot[t];
            int s = v;
#pragma unroll
            for (int d = 1; d < 64; d <<= 1) {
                int o = __shfl_up(s, d);
                if (t >= d) s += o;
            }
            int offs = s - v;            // exclusive scan = graph base
            base_[t] = offs + chunkbase[h * NGRAPH + t];
            lcnt[t] = 0;
            if (h == 0) offsets[t] = offs;
        }
        __syncthreads();
        for (int i = t; i < CHUNK_I4; i += 256) {
            int e4 = h * CHUNK_I4 + i;
            int4 r4 = ((const int4*)row)[e4];
            int4 c4 = ((const int4*)col)[e4];
            int rr[4] = {r4.x, r4.y, r4.z, r4.w};
            int cc[4] = {c4.x, c4.y, c4.z, c4.w};
#pragma unroll
            for (int u = 0; u < 4; ++u) {
                int g = rr[u] / perG;
                int lpos = atomicAdd(&lcnt[g], 1);
                sorted[(size_t)base_[g] + lpos] = make_uint2((unsigned)rr[u], (unsigned)cc[u]);
            }
        }
    } else {
        // ---------------- SX/SS role ----------------
        int s = (b / 5) * 4 + (r5 - 1);  // 0..1023
        int xcd = s & (NXCD - 1);
        int rem = s >> 3;                // 0..127
        int g = xcd * (NGRAPH / NXCD) + (rem >> 4);
        int split = rem & (SX_SPLIT - 1);
        int wid = t >> 6;
        int wslot = split * 4 + wid;     // 0..63
        int lane = t & 63;
        int k = lane >> 2;
        int sub = lane & 3;
        int f0 = sub * 16;
        int j0 = sub * 4;
        float accss[4] = {0.f, 0.f, 0.f, 0.f};
        float accsx[16];
#pragma unroll
        for (int j = 0; j < 16; ++j) accsx[j] = 0.f;
        size_t base = (size_t)g * perG;
#pragma unroll 2
        for (int nn = wslot; nn < perG; nn += 64) {
            size_t node = base + nn;
            float a = sel[node * K_DIMC + k];
            float4 s4 = *(const float4*)(sel + node * K_DIMC + j0);
            accss[0] += a * s4.x;
            accss[1] += a * s4.y;
            accss[2] += a * s4.z;
            accss[3] += a * s4.w;
            const float4* xv = (const float4*)(x + node * F_DIMC + f0);
#pragma unroll
            for (int j = 0; j < 4; ++j) {
                float4 v = xv[j];
                accsx[4 * j + 0] += a * v.x;
                accsx[4 * j + 1] += a * v.y;
                accsx[4 * j + 2] += a * v.z;
                accsx[4 * j + 3] += a * v.w;
            }
        }
        __shared__ float lsx[4][K_DIMC * F_DIMC];  // 16 KB
        __shared__ float lss[4][256];              // 4 KB
#pragma unroll
        for (int j4 = 0; j4 < 4; ++j4) {
            *(float4*)&lsx[wid][k * F_DIMC + f0 + 4 * j4] =
                make_float4(accsx[4 * j4], accsx[4 * j4 + 1], accsx[4 * j4 + 2], accsx[4 * j4 + 3]);
        }
        *(float4*)&lss[wid][k * K_DIMC + j0] = make_float4(accss[0], accss[1], accss[2], accss[3]);
        __syncthreads();
        for (int c = t; c < K_DIMC * F_DIMC; c += 256) {
            float sm = lsx[0][c] + lsx[1][c] + lsx[2][c] + lsx[3][c];
            atomicAdd(sxbuf + (size_t)g * (K_DIMC * F_DIMC) + c, sm);
        }
        {
            float sm = lss[0][t] + lss[1][t] + lss[2][t] + lss[3][t];
            atomicAdd(ssbuf + g * 256 + t, sm);
        }
    }
}

// ---- adj via MFMA with IN-KERNEL tile build: dense_raw[g] = A^T B per graph.
// 256 blocks (4/graph, XCD-grouped -> sel slice L2-resident), 4 waves.
// den[g] accumulated FREE from the fp32 A-halves before bf16 conversion.
__global__ __launch_bounds__(256) void k_adj(const uint2* __restrict__ sorted,
                                             const int* __restrict__ offsets,
                                             const int* __restrict__ gtot,
                                             const float* __restrict__ sel,
                                             float* __restrict__ dense_raw,
                                             float* __restrict__ den) {
    __shared__ unsigned short At[4][512];    // 32 edges x 16, edge-major
    __shared__ unsigned short Bt[4][512];
    __shared__ float lacc[4][256];
    __shared__ float qred[4];
    int b = blockIdx.x;
    int xcd = b & (NXCD - 1);
    int idx = b >> 3;                        // 0..31
    int g = xcd * (NGRAPH / NXCD) + (idx >> 2);
    int split = idx & 3;
    int t = threadIdx.x;
    int wid = t >> 6;
    int lane = t & 63;
    int m = lane & 15;
    int grp = lane >> 4;
    int half8 = (lane & 1) * 8;              // float offset of this lane's half-row

    int start = offsets[g];
    int cnt = gtot[g];
    int wslot = split * 4 + wid;             // 0..15
    f32x4 acc = {0.f, 0.f, 0.f, 0.f};
    float qacc = 0.f;
    int nch = (cnt + 31) >> 5;
    for (int ch = wslot; ch < nch; ch += 16) {
        int e0 = ch << 5;
        int eIdx = e0 + (lane >> 1);
        s16x8 av8 = {0, 0, 0, 0, 0, 0, 0, 0};
        s16x8 bv8 = {0, 0, 0, 0, 0, 0, 0, 0};
        if (eIdx < cnt) {
            uint2 pr = sorted[start + eIdx];
            const float4* ra = (const float4*)(sel + (size_t)pr.x * K_DIMC + half8);
            float4 a0 = ra[0], a1 = ra[1];
            qacc += a0.x * a0.x + a0.y * a0.y + a0.z * a0.z + a0.w * a0.w
                  + a1.x * a1.x + a1.y * a1.y + a1.z * a1.z + a1.w * a1.w;
            av8[0] = (short)f2bf(a0.x); av8[1] = (short)f2bf(a0.y);
            av8[2] = (short)f2bf(a0.z); av8[3] = (short)f2bf(a0.w);
            av8[4] = (short)f2bf(a1.x); av8[5] = (short)f2bf(a1.y);
            av8[6] = (short)f2bf(a1.z); av8[7] = (short)f2bf(a1.w);
            const float4* rb = (const float4*)(sel + (size_t)pr.y * K_DIMC + half8);
            float4 b0 = rb[0], b1 = rb[1];
            bv8[0] = (short)f2bf(b0.x); bv8[1] = (short)f2bf(b0.y);
            bv8[2] = (short)f2bf(b0.z); bv8[3] = (short)f2bf(b0.w);
            bv8[4] = (short)f2bf(b1.x); bv8[5] = (short)f2bf(b1.y);
            bv8[6] = (short)f2bf(b1.z); bv8[7] = (short)f2bf(b1.w);
        }
        ((s16x8*)At[wid])[lane] = av8;
        ((s16x8*)Bt[wid])[lane] = bv8;
        // per-wave LDS write->read; compiler inserts lgkmcnt (r19-21 verified)
        s16x8 av, bv;
#pragma unroll
        for (int d = 0; d < 8; ++d) {
            int off = (8 * grp + d) * K_DIMC + m;
            av[d] = (short)At[wid][off];
            bv[d] = (short)Bt[wid][off];
        }
        acc = __builtin_amdgcn_mfma_f32_16x16x32_bf16(av, bv, acc, 0, 0, 0);
    }
    // C layout (m89): col = lane&15, row = (lane>>4)*4 + reg
#pragma unroll
    for (int d = 0; d < 4; ++d) {
        lacc[wid][(4 * grp + d) * K_DIMC + m] = acc[d];
    }
#pragma unroll
    for (int off = 32; off > 0; off >>= 1) qacc += __shfl_down(qacc, off);
    if (lane == 0) qred[wid] = qacc;
    __syncthreads();
    float s = lacc[0][t] + lacc[1][t] + lacc[2][t] + lacc[3][t];
    atomicAdd(dense_raw + g * 256 + t, s);   // 4 contenders/cell
    if (t == 0) {
        atomicAdd(den + g, qred[0] + qred[1] + qred[2] + qred[3]);
    }
}

// ---- finalize: normalize adj, copy SX to out, losses via ws + last-block write ----
__global__ __launch_bounds__(256) void k_fin(const float* __restrict__ dense_raw,
                                             const float* __restrict__ ssbuf,
                                             const float* __restrict__ sxbuf,
                                             const float* __restrict__ den,
                                             float* __restrict__ lossws,
                                             int* __restrict__ donecnt,
                                             float* __restrict__ out) {
    int g = blockIdx.x;
    int c = threadIdx.x;
    int k = c >> 4, j = c & 15;
    int lane = threadIdx.x & 63;
    int wid = threadIdx.x >> 6;

    ((float4*)(out + (size_t)g * (K_DIMC * F_DIMC)))[c] =
        ((const float4*)(sxbuf + (size_t)g * (K_DIMC * F_DIMC)))[c];

    float a = dense_raw[g * 256 + c];
    float s = a;
    s += __shfl_xor(s, 1);
    s += __shfl_xor(s, 2);
    s += __shfl_xor(s, 4);
    s += __shfl_xor(s, 8);
    __shared__ float dvrow[K_DIMC];
    if (j == 0) dvrow[k] = sqrtf(s) + 1e-15f;
    __syncthreads();
    float v = a / (dvrow[k] * dvrow[j]);
    out[ADJ_OFF + g * 256 + c] = v;

    float ss = ssbuf[g * 256 + c];
    float tt = (k == j) ? v : 0.f;
    float n2 = ss * ss;
#pragma unroll
    for (int off = 32; off > 0; off >>= 1) {
        tt += __shfl_down(tt, off);
        n2 += __shfl_down(n2, off);
    }
    __shared__ float redt[4], redn[4];
    if (lane == 0) { redt[wid] = tt; redn[wid] = n2; }
    __syncthreads();
    float tr = redt[0] + redt[1] + redt[2] + redt[3];
    float nrm2 = redn[0] + redn[1] + redn[2] + redn[3];
    float invn = 1.f / sqrtf(nrm2);
    float d = ss * invn - ((k == j) ? 0.25f : 0.f);
    float o2 = d * d;
#pragma unroll
    for (int off = 32; off > 0; off >>= 1) o2 += __shfl_down(o2, off);
    __shared__ float redo[4];
    if (lane == 0) redo[wid] = o2;
    __syncthreads();
    if (threadIdx.x == 0) {
        float osum = redo[0] + redo[1] + redo[2] + redo[3];
        float og = sqrtf(osum);
        float mterm = -(tr / den[g]);
        atomicAdd(lossws + 0, mterm * (1.f / NGRAPH));
        atomicAdd(lossws + 1, og * (1.f / NGRAPH));
        __threadfence();
        int old = atomicAdd(donecnt, 1);
        if (old == NGRAPH - 1) {
            float l0 = atomicAdd(lossws + 0, 0.f);
            float l1 = atomicAdd(lossws + 1, 0.f);
            out[LOSS_OFF + 0] = l0;
            out[LOSS_OFF + 1] = l1;
        }
    }
}

extern "C" void kernel_launch(void* const* d_in, const int* in_sizes, int n_in,
                              void* d_out, int out_size, void* d_ws, size_t ws_size,
                              hipStream_t stream) {
    const float* node_attr = (const float*)d_in[0];
    const float* W = (const float*)d_in[1];
    const float* bias = (const float*)d_in[2];
    const int* edge_index = (const int*)d_in[3];
    int N = in_sizes[0] / F_DIMC;
    int E = in_sizes[3] / 2;
    int perG = N / NGRAPH;
    const int* row = edge_index;
    const int* col = edge_index + E;
    float* out = (float*)d_out;
    char* ws = (char*)d_ws;

    float* den = (float*)(ws + 0);
    int* donecnt = (int*)(ws + 256);
    float* lossws = (float*)(ws + 512);
    float* dense_raw = (float*)(ws + 1024);
    float* ssbuf = (float*)(ws + 66560);
    float* sxbuf = (float*)(ws + 132096);
    int* offsets = (int*)(ws + 394240);
    int* gtot = (int*)(ws + 394496);
    int* blockhist = (int*)(ws + 394752);
    int* chunkbase = (int*)(ws + 460288);
    float* sel = (float*)(ws + 525824);
    uint2* sorted = (uint2*)(ws + 7079424);

    k_sel_hist<<<NB_SEL + NB_CHUNK + NB_ZERO, 256, 0, stream>>>(node_attr, W, bias, row, sel,
                                                                blockhist, (float4*)ws, N, perG);
    k_chunkscan<<<NGRAPH, 256, 0, stream>>>(blockhist, chunkbase, gtot);
    k_scatter_sx<<<NB_CHUNK * 5, 256, 0, stream>>>(row, col, gtot, chunkbase, offsets,
                                                   sorted, sel, node_attr, ssbuf, sxbuf, perG);
    k_adj<<<ADJ_BLOCKS, 256, 0, stream>>>(sorted, offsets, gtot, sel, dense_raw, den);
    k_fin<<<NGRAPH, 256, 0, stream>>>(dense_raw, ssbuf, sxbuf, den, lossws, donecnt, out);
}

// Round 23
// 83.406 us; speedup vs baseline: 1.0350x; 1.0350x over previous
//
#include <hip/hip_runtime.h>

#define F_DIMC 64
#define K_DIMC 16
#define NGRAPH 64
#define NXCD 8
#define SX_SPLIT 16
#define NB_SEL 400                         // N/256
#define NB_CHUNK 256                       // histogram/scatter chunks
#define NB_ZERO 64
#define CHUNK_I4 800                       // int4s per chunk (256*800 = E/4)
#define ADJ_BLOCKS 512                     // 8/graph, 2/CU
#define ADJ_OFF (NGRAPH * K_DIMC * F_DIMC)
#define LOSS_OFF (ADJ_OFF + NGRAPH * K_DIMC * K_DIMC)
#define ZERO_BYTES 394240

typedef __attribute__((ext_vector_type(8))) short s16x8;
typedef __attribute__((ext_vector_type(4))) float f32x4;

// ---------------- workspace layout (bytes) ----------------
// zeroed each call (zero-role blocks of k_sel_hist): [0, 394240)
//   [0,256) den | [256,512) donecnt | [512,768) lossws | [768,1024) gdone (int[64])
//   [1024,66560) dense_raw | [66560,132096) ssbuf | [132096,394240) sxbuf
// not zeroed:
//   [394240,394496) offsets | [394496,394752) gtot
//   [394752,460288) blockhist (int[256][64]) | [460288,525824) chunkbase
//   [525824,7079424) sel (float[N*16]) | [7079424,13633024) sorted (uint2[E])

__device__ inline unsigned short f2bf(float f) {
    unsigned u = __builtin_bit_cast(unsigned, f);
    u += 0x7fffu + ((u >> 16) & 1u);       // RNE
    return (unsigned short)(u >> 16);
}

// ---- fused: selection [0,NB_SEL) || per-chunk histogram || ws zeroing ----
__global__ __launch_bounds__(256) void k_sel_hist(const float* __restrict__ node_attr,
                                                  const float* __restrict__ W,
                                                  const float* __restrict__ bias,
                                                  const int* __restrict__ row,
                                                  float* __restrict__ sel,
                                                  int* __restrict__ blockhist,
                                                  float4* __restrict__ zdst,
                                                  int N, int perG) {
    int t = threadIdx.x;
    if (blockIdx.x < NB_SEL) {
        __shared__ float sW[K_DIMC][F_DIMC];
        __shared__ float sb[K_DIMC];
        for (int idx = t; idx < F_DIMC * K_DIMC; idx += 256) {
            int f = idx / K_DIMC, k = idx % K_DIMC;
            sW[k][f] = W[idx];
        }
        if (t < K_DIMC) sb[t] = bias[t];
        __syncthreads();
        int n = blockIdx.x * 256 + t;
        if (n >= N) return;

        const float4* xr = (const float4*)(node_attr + (size_t)n * F_DIMC);
        float4 x[F_DIMC / 4];
#pragma unroll
        for (int f4 = 0; f4 < F_DIMC / 4; ++f4) x[f4] = xr[f4];

        float logits[K_DIMC];
#pragma unroll
        for (int k = 0; k < K_DIMC; ++k) {
            const float4* wk = (const float4*)&sW[k][0];
            float acc = sb[k];
#pragma unroll
            for (int f4 = 0; f4 < F_DIMC / 4; ++f4) {
                float4 w = wk[f4];
                acc += x[f4].x * w.x + x[f4].y * w.y + x[f4].z * w.z + x[f4].w * w.w;
            }
            logits[k] = acc;
        }
        float m = logits[0];
#pragma unroll
        for (int k = 1; k < K_DIMC; ++k) m = fmaxf(m, logits[k]);
        float sum = 0.f;
#pragma unroll
        for (int k = 0; k < K_DIMC; ++k) {
            float e = __expf(logits[k] - m);
            logits[k] = e;
            sum += e;
        }
        float inv = 1.f / sum;
        float4* sd = (float4*)(sel + (size_t)n * K_DIMC);
#pragma unroll
        for (int k4 = 0; k4 < K_DIMC / 4; ++k4) {
            float4 v;
            v.x = logits[4 * k4 + 0] * inv;
            v.y = logits[4 * k4 + 1] * inv;
            v.z = logits[4 * k4 + 2] * inv;
            v.w = logits[4 * k4 + 3] * inv;
            sd[k4] = v;
        }
    } else if (blockIdx.x < NB_SEL + NB_CHUNK) {
        __shared__ int lh[NGRAPH];
        int h = blockIdx.x - NB_SEL;                 // 0..255, static chunk
        if (t < NGRAPH) lh[t] = 0;
        __syncthreads();
        for (int i = t; i < CHUNK_I4; i += 256) {
            int4 r4 = ((const int4*)row)[h * CHUNK_I4 + i];
            atomicAdd(&lh[r4.x / perG], 1);
            atomicAdd(&lh[r4.y / perG], 1);
            atomicAdd(&lh[r4.z / perG], 1);
            atomicAdd(&lh[r4.w / perG], 1);
        }
        __syncthreads();
        if (t < NGRAPH) blockhist[h * NGRAPH + t] = lh[t];
    } else {
        int z = blockIdx.x - NB_SEL - NB_CHUNK;
        for (int i = z * 256 + t; i < ZERO_BYTES / 16; i += NB_ZERO * 256)
            zdst[i] = make_float4(0.f, 0.f, 0.f, 0.f);
    }
}

// ---- per-graph exclusive scan over 256 chunks: chunkbase[b][g], gtot[g] ----
__global__ __launch_bounds__(256) void k_chunkscan(const int* __restrict__ blockhist,
                                                   int* __restrict__ chunkbase,
                                                   int* __restrict__ gtot) {
    int g = blockIdx.x;
    int t = threadIdx.x;                 // 0..255 = chunk index
    int lane = t & 63;
    int wid = t >> 6;
    int v = blockhist[t * NGRAPH + g];
    int s = v;
#pragma unroll
    for (int d = 1; d < 64; d <<= 1) {
        int o = __shfl_up(s, d);
        if (lane >= d) s += o;
    }
    __shared__ int wsum[4];
    if (lane == 63) wsum[wid] = s;
    __syncthreads();
    int pre = 0;
#pragma unroll
    for (int w = 0; w < 4; ++w) pre += (w < wid) ? wsum[w] : 0;
    int incl = s + pre;
    chunkbase[t * NGRAPH + g] = incl - v;
    if (t == 255) gtot[g] = incl;
}

// ---- fused scatter || SX/SS, 5-stride role interleave ----
__global__ __launch_bounds__(256) void k_scatter_sx(const int* __restrict__ row,
                                                    const int* __restrict__ col,
                                                    const int* __restrict__ gtot,
                                                    const int* __restrict__ chunkbase,
                                                    int* __restrict__ offsets,
                                                    uint2* __restrict__ sorted,
                                                    const float* __restrict__ sel,
                                                    const float* __restrict__ x,
                                                    float* __restrict__ ssbuf,
                                                    float* __restrict__ sxbuf,
                                                    int perG) {
    int b = blockIdx.x;
    int r5 = b % 5;
    int t = threadIdx.x;
    if (r5 == 0) {
        // ---------------- scatter role ----------------
        __shared__ int base_[NGRAPH];
        __shared__ int lcnt[NGRAPH];
        int h = b / 5;                   // 0..255, same chunk as hist
        if (t < 64) {
            int v = gtot[t];
            int s = v;
#pragma unroll
            for (int d = 1; d < 64; d <<= 1) {
                int o = __shfl_up(s, d);
                if (t >= d) s += o;
            }
            int offs = s - v;            // exclusive scan = graph base
            base_[t] = offs + chunkbase[h * NGRAPH + t];
            lcnt[t] = 0;
            if (h == 0) offsets[t] = offs;
        }
        __syncthreads();
        for (int i = t; i < CHUNK_I4; i += 256) {
            int e4 = h * CHUNK_I4 + i;
            int4 r4 = ((const int4*)row)[e4];
            int4 c4 = ((const int4*)col)[e4];
            int rr[4] = {r4.x, r4.y, r4.z, r4.w};
            int cc[4] = {c4.x, c4.y, c4.z, c4.w};
#pragma unroll
            for (int u = 0; u < 4; ++u) {
                int g = rr[u] / perG;
                int lpos = atomicAdd(&lcnt[g], 1);
                sorted[(size_t)base_[g] + lpos] = make_uint2((unsigned)rr[u], (unsigned)cc[u]);
            }
        }
    } else {
        // ---------------- SX/SS role ----------------
        int s = (b / 5) * 4 + (r5 - 1);  // 0..1023
        int xcd = s & (NXCD - 1);
        int rem = s >> 3;                // 0..127
        int g = xcd * (NGRAPH / NXCD) + (rem >> 4);
        int split = rem & (SX_SPLIT - 1);
        int wid = t >> 6;
        int wslot = split * 4 + wid;     // 0..63
        int lane = t & 63;
        int k = lane >> 2;
        int sub = lane & 3;
        int f0 = sub * 16;
        int j0 = sub * 4;
        float accss[4] = {0.f, 0.f, 0.f, 0.f};
        float accsx[16];
#pragma unroll
        for (int j = 0; j < 16; ++j) accsx[j] = 0.f;
        size_t base = (size_t)g * perG;
#pragma unroll 2
        for (int nn = wslot; nn < perG; nn += 64) {
            size_t node = base + nn;
            float a = sel[node * K_DIMC + k];
            float4 s4 = *(const float4*)(sel + node * K_DIMC + j0);
            accss[0] += a * s4.x;
            accss[1] += a * s4.y;
            accss[2] += a * s4.z;
            accss[3] += a * s4.w;
            const float4* xv = (const float4*)(x + node * F_DIMC + f0);
#pragma unroll
            for (int j = 0; j < 4; ++j) {
                float4 v = xv[j];
                accsx[4 * j + 0] += a * v.x;
                accsx[4 * j + 1] += a * v.y;
                accsx[4 * j + 2] += a * v.z;
                accsx[4 * j + 3] += a * v.w;
            }
        }
        __shared__ float lsx[4][K_DIMC * F_DIMC];  // 16 KB
        __shared__ float lss[4][256];              // 4 KB
#pragma unroll
        for (int j4 = 0; j4 < 4; ++j4) {
            *(float4*)&lsx[wid][k * F_DIMC + f0 + 4 * j4] =
                make_float4(accsx[4 * j4], accsx[4 * j4 + 1], accsx[4 * j4 + 2], accsx[4 * j4 + 3]);
        }
        *(float4*)&lss[wid][k * K_DIMC + j0] = make_float4(accss[0], accss[1], accss[2], accss[3]);
        __syncthreads();
        for (int c = t; c < K_DIMC * F_DIMC; c += 256) {
            float sm = lsx[0][c] + lsx[1][c] + lsx[2][c] + lsx[3][c];
            atomicAdd(sxbuf + (size_t)g * (K_DIMC * F_DIMC) + c, sm);
        }
        {
            float sm = lss[0][t] + lss[1][t] + lss[2][t] + lss[3][t];
            atomicAdd(ssbuf + g * 256 + t, sm);
        }
    }
}

// ---- adj via MFMA + per-graph LAST-BLOCK FINALIZE (k_fin merged).
// 512 blocks (8/graph, XCD-grouped, 2/CU), 4 waves. Per 32-edge tile:
// lane = edge-half -> dense f4 gathers + bf16 convert + ds_write; 16
// ds_read_u16 frag reads; 1 MFMA. den free from fp32 A-halves.
// After the block's dense_raw/den atomics: fence + gdone[g] ticket; the
// 8th block of graph g runs the finalize (normalize/trace/ortho/losses).
__global__ __launch_bounds__(256) void k_adj(const uint2* __restrict__ sorted,
                                             const int* __restrict__ offsets,
                                             const int* __restrict__ gtot,
                                             const float* __restrict__ sel,
                                             float* __restrict__ dense_raw,
                                             float* __restrict__ den,
                                             const float* __restrict__ ssbuf,
                                             const float* __restrict__ sxbuf,
                                             float* __restrict__ lossws,
                                             int* __restrict__ donecnt,
                                             int* __restrict__ gdone,
                                             float* __restrict__ out) {
    __shared__ unsigned short At[4][512];    // 32 edges x 16, edge-major
    __shared__ unsigned short Bt[4][512];
    __shared__ float lacc[4][256];
    __shared__ float qred[4];
    __shared__ int lastFlag;
    int b = blockIdx.x;
    int xcd = b & (NXCD - 1);
    int idx = b >> 3;                        // 0..63
    int g = xcd * (NGRAPH / NXCD) + (idx >> 3);
    int split = idx & 7;                     // 0..7
    int t = threadIdx.x;
    int wid = t >> 6;
    int lane = t & 63;
    int m = lane & 15;
    int grp = lane >> 4;
    int half8 = (lane & 1) * 8;              // float offset of this lane's half-row

    int start = offsets[g];
    int cnt = gtot[g];
    int wslot = split * 4 + wid;             // 0..31
    f32x4 acc = {0.f, 0.f, 0.f, 0.f};
    float qacc = 0.f;
    int nch = (cnt + 31) >> 5;
    for (int ch = wslot; ch < nch; ch += 32) {
        int e0 = ch << 5;
        int eIdx = e0 + (lane >> 1);
        s16x8 av8 = {0, 0, 0, 0, 0, 0, 0, 0};
        s16x8 bv8 = {0, 0, 0, 0, 0, 0, 0, 0};
        if (eIdx < cnt) {
            uint2 pr = sorted[start + eIdx];
            const float4* ra = (const float4*)(sel + (size_t)pr.x * K_DIMC + half8);
            float4 a0 = ra[0], a1 = ra[1];
            qacc += a0.x * a0.x + a0.y * a0.y + a0.z * a0.z + a0.w * a0.w
                  + a1.x * a1.x + a1.y * a1.y + a1.z * a1.z + a1.w * a1.w;
            av8[0] = (short)f2bf(a0.x); av8[1] = (short)f2bf(a0.y);
            av8[2] = (short)f2bf(a0.z); av8[3] = (short)f2bf(a0.w);
            av8[4] = (short)f2bf(a1.x); av8[5] = (short)f2bf(a1.y);
            av8[6] = (short)f2bf(a1.z); av8[7] = (short)f2bf(a1.w);
            const float4* rb = (const float4*)(sel + (size_t)pr.y * K_DIMC + half8);
            float4 b0 = rb[0], b1 = rb[1];
            bv8[0] = (short)f2bf(b0.x); bv8[1] = (short)f2bf(b0.y);
            bv8[2] = (short)f2bf(b0.z); bv8[3] = (short)f2bf(b0.w);
            bv8[4] = (short)f2bf(b1.x); bv8[5] = (short)f2bf(b1.y);
            bv8[6] = (short)f2bf(b1.z); bv8[7] = (short)f2bf(b1.w);
        }
        ((s16x8*)At[wid])[lane] = av8;
        ((s16x8*)Bt[wid])[lane] = bv8;
        s16x8 av, bv;
#pragma unroll
        for (int d = 0; d < 8; ++d) {
            int off = (8 * grp + d) * K_DIMC + m;
            av[d] = (short)At[wid][off];
            bv[d] = (short)Bt[wid][off];
        }
        acc = __builtin_amdgcn_mfma_f32_16x16x32_bf16(av, bv, acc, 0, 0, 0);
    }
    // C layout (m89): col = lane&15, row = (lane>>4)*4 + reg
#pragma unroll
    for (int d = 0; d < 4; ++d) {
        lacc[wid][(4 * grp + d) * K_DIMC + m] = acc[d];
    }
#pragma unroll
    for (int off = 32; off > 0; off >>= 1) qacc += __shfl_down(qacc, off);
    if (lane == 0) qred[wid] = qacc;
    __syncthreads();
    float s = lacc[0][t] + lacc[1][t] + lacc[2][t] + lacc[3][t];
    atomicAdd(dense_raw + g * 256 + t, s);   // 8 contenders/cell
    if (t == 0) {
        atomicAdd(den + g, qred[0] + qred[1] + qred[2] + qred[3]);
        __threadfence();
        int old = atomicAdd(&gdone[g], 1);
        lastFlag = (old == 7);               // last of the graph's 8 blocks
    }
    __syncthreads();
    if (!lastFlag) return;

    // ---------------- finalize for graph g (former k_fin body) ----------------
    {
        int c = t;
        int k = c >> 4, j = c & 15;

        ((float4*)(out + (size_t)g * (K_DIMC * F_DIMC)))[c] =
            ((const float4*)(sxbuf + (size_t)g * (K_DIMC * F_DIMC)))[c];

        float a = dense_raw[g * 256 + c];
        float rs = a;
        rs += __shfl_xor(rs, 1);
        rs += __shfl_xor(rs, 2);
        rs += __shfl_xor(rs, 4);
        rs += __shfl_xor(rs, 8);
        __shared__ float dvrow[K_DIMC];
        if (j == 0) dvrow[k] = sqrtf(rs) + 1e-15f;
        __syncthreads();
        float v = a / (dvrow[k] * dvrow[j]);
        out[ADJ_OFF + g * 256 + c] = v;

        float ss = ssbuf[g * 256 + c];
        float tt = (k == j) ? v : 0.f;
        float n2 = ss * ss;
#pragma unroll
        for (int off = 32; off > 0; off >>= 1) {
            tt += __shfl_down(tt, off);
            n2 += __shfl_down(n2, off);
        }
        __shared__ float redt[4], redn[4];
        if (lane == 0) { redt[wid] = tt; redn[wid] = n2; }
        __syncthreads();
        float tr = redt[0] + redt[1] + redt[2] + redt[3];
        float nrm2 = redn[0] + redn[1] + redn[2] + redn[3];
        float invn = 1.f / sqrtf(nrm2);
        float dd = ss * invn - ((k == j) ? 0.25f : 0.f);
        float o2 = dd * dd;
#pragma unroll
        for (int off = 32; off > 0; off >>= 1) o2 += __shfl_down(o2, off);
        __shared__ float redo[4];
        if (lane == 0) redo[wid] = o2;
        __syncthreads();
        if (t == 0) {
            float osum = redo[0] + redo[1] + redo[2] + redo[3];
            float og = sqrtf(osum);
            float mterm = -(tr / den[g]);
            atomicAdd(lossws + 0, mterm * (1.f / NGRAPH));
            atomicAdd(lossws + 1, og * (1.f / NGRAPH));
            __threadfence();
            int old = atomicAdd(donecnt, 1);
            if (old == NGRAPH - 1) {
                float l0 = atomicAdd(lossws + 0, 0.f);
                float l1 = atomicAdd(lossws + 1, 0.f);
                out[LOSS_OFF + 0] = l0;
                out[LOSS_OFF + 1] = l1;
            }
        }
    }
}

extern "C" void kernel_launch(void* const* d_in, const int* in_sizes, int n_in,
                              void* d_out, int out_size, void* d_ws, size_t ws_size,
                              hipStream_t stream) {
    const float* node_attr = (const float*)d_in[0];
    const float* W = (const float*)d_in[1];
    const float* bias = (const float*)d_in[2];
    const int* edge_index = (const int*)d_in[3];
    int N = in_sizes[0] / F_DIMC;
    int E = in_sizes[3] / 2;
    int perG = N / NGRAPH;
    const int* row = edge_index;
    const int* col = edge_index + E;
    float* out = (float*)d_out;
    char* ws = (char*)d_ws;

    float* den = (float*)(ws + 0);
    int* donecnt = (int*)(ws + 256);
    float* lossws = (float*)(ws + 512);
    int* gdone = (int*)(ws + 768);
    float* dense_raw = (float*)(ws + 1024);
    float* ssbuf = (float*)(ws + 66560);
    float* sxbuf = (float*)(ws + 132096);
    int* offsets = (int*)(ws + 394240);
    int* gtot = (int*)(ws + 394496);
    int* blockhist = (int*)(ws + 394752);
    int* chunkbase = (int*)(ws + 460288);
    float* sel = (float*)(ws + 525824);
    uint2* sorted = (uint2*)(ws + 7079424);

    k_sel_hist<<<NB_SEL + NB_CHUNK + NB_ZERO, 256, 0, stream>>>(node_attr, W, bias, row, sel,
                                                                blockhist, (float4*)ws, N, perG);
    k_chunkscan<<<NGRAPH, 256, 0, stream>>>(blockhist, chunkbase, gtot);
    k_scatter_sx<<<NB_CHUNK * 5, 256, 0, stream>>>(row, col, gtot, chunkbase, offsets,
                                                   sorted, sel, node_attr, ssbuf, sxbuf, perG);
    k_adj<<<ADJ_BLOCKS, 256, 0, stream>>>(sorted, offsets, gtot, sel, dense_raw, den,
                                          ssbuf, sxbuf, lossws, donecnt, gdone, out);
}